// Round 1
// baseline (1432.895 us; speedup 1.0000x reference)
//
#include <hip/hip_runtime.h>

#define HW 65536

__device__ __forceinline__ int refl(int i){ if (i < 0) i = -i; if (i > 255) i = 510 - i; return i; }
__device__ __forceinline__ float lrelu(float x){ return x > 0.f ? x : 0.01f * x; }

// ---------------- K1: bilinear grid sample (border, align_corners=False) ----------------
__global__ __launch_bounds__(256) void k_gridsample(const float* __restrict__ img,
                                                    const float* __restrict__ zern,
                                                    float* __restrict__ tilt){
  int x = threadIdx.x, y = blockIdx.x;
  int pix = y * 256 + x;
  float px = zern[pix * 35 + 0], py = zern[pix * 35 + 1];
  float ix = ((float)x + px) * (256.f / 255.f) - 0.5f;
  float iy = ((float)y + py) * (256.f / 255.f) - 0.5f;
  ix = fminf(fmaxf(ix, 0.f), 255.f);
  iy = fminf(fmaxf(iy, 0.f), 255.f);
  float x0f = floorf(ix), y0f = floorf(iy);
  float wx = ix - x0f, wy = iy - y0f;
  int x0 = (int)x0f, y0 = (int)y0f;
  int x1 = min(x0 + 1, 255), y1 = min(y0 + 1, 255);
  #pragma unroll
  for (int c = 0; c < 3; ++c){
    const float* im = img + c * HW;
    float g00 = im[y0 * 256 + x0], g01 = im[y0 * 256 + x1];
    float g10 = im[y1 * 256 + x0], g11 = im[y1 * 256 + x1];
    float top = g00 * (1.f - wx) + g01 * wx;
    float bot = g10 * (1.f - wx) + g11 * wx;
    tilt[c * HW + pix] = top * (1.f - wy) + bot * wy;
  }
}

// ---------------- K2: per-pixel MLP 33 -> 200 -> 200 -> 100, writes coef plane-major ----
__global__ __launch_bounds__(256) void k_mlp(const float* __restrict__ zern,
    const float* __restrict__ w1, const float* __restrict__ b1,
    const float* __restrict__ w2, const float* __restrict__ b2,
    const float* __restrict__ w3, const float* __restrict__ b3,
    float* __restrict__ coefp){
  __shared__ float sf[32][33];
  __shared__ float sh1[32][201];
  __shared__ float sh2[32][201];
  int tid = threadIdx.x;
  int pix0 = blockIdx.x * 32;
  for (int e = tid; e < 32 * 33; e += 256){
    int p = e / 33, k = e - p * 33;
    sf[p][k] = zern[(pix0 + p) * 35 + 2 + k];
  }
  __syncthreads();
  int pg = tid & 15, og = tid >> 4;
  int p0 = pg * 2;
  // layer 1: 33 -> 200
  {
    float acc0[13], acc1[13];
    #pragma unroll
    for (int i = 0; i < 13; ++i){ int o = og + 16 * i; float b = (o < 200) ? b1[o] : 0.f; acc0[i] = b; acc1[i] = b; }
    for (int k = 0; k < 33; ++k){
      float a0 = sf[p0][k], a1 = sf[p0 + 1][k];
      #pragma unroll
      for (int i = 0; i < 13; ++i){
        int o = og + 16 * i;
        if (o < 200){ float wv = w1[o * 33 + k]; acc0[i] += a0 * wv; acc1[i] += a1 * wv; }
      }
    }
    #pragma unroll
    for (int i = 0; i < 13; ++i){
      int o = og + 16 * i;
      if (o < 200){ sh1[p0][o] = lrelu(acc0[i]); sh1[p0 + 1][o] = lrelu(acc1[i]); }
    }
  }
  __syncthreads();
  // layer 2: 200 -> 200
  {
    float acc0[13], acc1[13];
    #pragma unroll
    for (int i = 0; i < 13; ++i){ int o = og + 16 * i; float b = (o < 200) ? b2[o] : 0.f; acc0[i] = b; acc1[i] = b; }
    for (int k = 0; k < 200; ++k){
      float a0 = sh1[p0][k], a1 = sh1[p0 + 1][k];
      #pragma unroll
      for (int i = 0; i < 13; ++i){
        int o = og + 16 * i;
        if (o < 200){ float wv = w2[o * 200 + k]; acc0[i] += a0 * wv; acc1[i] += a1 * wv; }
      }
    }
    #pragma unroll
    for (int i = 0; i < 13; ++i){
      int o = og + 16 * i;
      if (o < 200){ sh2[p0][o] = lrelu(acc0[i]); sh2[p0 + 1][o] = lrelu(acc1[i]); }
    }
  }
  __syncthreads();
  // layer 3: 200 -> 100 (no activation)
  {
    float acc0[7], acc1[7];
    #pragma unroll
    for (int i = 0; i < 7; ++i){ int o = og + 16 * i; float b = (o < 100) ? b3[o] : 0.f; acc0[i] = b; acc1[i] = b; }
    for (int k = 0; k < 200; ++k){
      float a0 = sh2[p0][k], a1 = sh2[p0 + 1][k];
      #pragma unroll
      for (int i = 0; i < 7; ++i){
        int o = og + 16 * i;
        if (o < 100){ float wv = w3[o * 200 + k]; acc0[i] += a0 * wv; acc1[i] += a1 * wv; }
      }
    }
    #pragma unroll
    for (int i = 0; i < 7; ++i){
      int o = og + 16 * i;
      if (o < 100){
        coefp[o * HW + pix0 + p0]     = acc0[i];
        coefp[o * HW + pix0 + p0 + 1] = acc1[i];
      }
    }
  }
}

// ---------------- K3: vertical 65-tap conv (reflect), per channel-class c ----------------
// c in {0,1,2}: planes q<100: X = tilt_c * coef_q, L = basis_left[:, q/10]
//               planes 100..109: X = tilt_c, L = mu[:, q-100]
// c == 3:       planes q<100: X = coef_q, L = basis_left[:, q/10]
__global__ __launch_bounds__(256) void k_vconv(const float* __restrict__ tilt,
    const float* __restrict__ coefp, const float* __restrict__ bl,
    const float* __restrict__ mu, float* __restrict__ vbuf, int c){
  __shared__ float sx[128][97];
  __shared__ float sL[65];
  int tid = threadIdx.x;
  int q  = blockIdx.x >> 4;
  int ti = blockIdx.x & 15;
  int yt = ti >> 1, xt = ti & 1;
  int x0g = xt * 128;
  int ybase = yt * 32 - 32;
  if (tid < 65){
    float kv;
    if (c == 3 || q < 100) kv = bl[tid * 10 + q / 10];
    else                   kv = mu[tid * 10 + (q - 100)];
    sL[tid] = kv;
  }
  const float* tc = tilt + c * HW;
  const float* cq = coefp + q * HW;
  for (int e = tid; e < 96 * 128; e += 256){
    int yy = e >> 7, cxx = e & 127;
    int yin = refl(ybase + yy);
    int g = yin * 256 + x0g + cxx;
    float v;
    if (c < 3){ v = tc[g]; if (q < 100) v *= cq[g]; }
    else        v = cq[g];
    sx[cxx][yy] = v;
  }
  __syncthreads();
  int cx = tid & 127, ys = tid >> 7;
  int yb = ys * 16;
  float acc[16];
  #pragma unroll
  for (int t = 0; t < 16; ++t) acc[t] = 0.f;
  for (int u = 0; u < 64; u += 4){
    float w[20];
    #pragma unroll
    for (int r2 = 0; r2 < 20; ++r2) w[r2] = sx[cx][yb + u + r2];
    float k0 = sL[u], k1 = sL[u + 1], k2 = sL[u + 2], k3 = sL[u + 3];
    #pragma unroll
    for (int t = 0; t < 16; ++t)
      acc[t] += k0 * w[t] + k1 * w[t + 1] + k2 * w[t + 2] + k3 * w[t + 3];
  }
  float k64 = sL[64];
  #pragma unroll
  for (int t = 0; t < 16; ++t) acc[t] += k64 * sx[cx][yb + 64 + t];
  int yo = yt * 32 + yb;
  #pragma unroll
  for (int t = 0; t < 16; ++t)
    vbuf[q * HW + (yo + t) * 256 + x0g + cx] = acc[t];
}

// ---------------- K4: horizontal 65-tap conv (reflect) + accumulate over planes ---------
__global__ __launch_bounds__(256) void k_hconv(const float* __restrict__ vbuf,
    const float* __restrict__ br, const float* __restrict__ mu,
    float* __restrict__ accb, int c){
  __shared__ __align__(16) float sr[4][320];
  __shared__ float sR[65];
  int tid = threadIdx.x;
  int g  = blockIdx.x >> 6;
  int yt = blockIdx.x & 63;
  int r = tid >> 6, xg = tid & 63, x0 = xg * 4;
  float a0 = 0.f, a1 = 0.f, a2 = 0.f, a3 = 0.f;
  for (int bb = 0; bb < 10; ++bb){
    int q; const float* kp;
    if (c < 3){
      if (g < 10){ q = g * 10 + bb; kp = br; }
      else        { q = 100 + bb;    kp = mu; }
    } else        { q = g * 10 + bb; kp = br; }
    __syncthreads();
    if (tid < 65) sR[tid] = kp[tid * 10 + bb];
    for (int e = tid; e < 4 * 320; e += 256){
      int rr = e / 320, i = e - rr * 320;
      int xin = refl(i - 32);
      sr[rr][i] = vbuf[q * HW + (yt * 4 + rr) * 256 + xin];
    }
    __syncthreads();
    float4 av = *(const float4*)&sr[r][x0];
    for (int u = 0; u < 64; u += 4){
      float4 bv = *(const float4*)&sr[r][x0 + u + 4];
      float k0 = sR[u], k1 = sR[u + 1], k2 = sR[u + 2], k3 = sR[u + 3];
      a0 += k0 * av.x + k1 * av.y + k2 * av.z + k3 * av.w;
      a1 += k0 * av.y + k1 * av.z + k2 * av.w + k3 * bv.x;
      a2 += k0 * av.z + k1 * av.w + k2 * bv.x + k3 * bv.y;
      a3 += k0 * av.w + k1 * bv.x + k2 * bv.y + k3 * bv.z;
      av = bv;
    }
    float k64 = sR[64];
    a0 += k64 * av.x; a1 += k64 * av.y; a2 += k64 * av.z; a3 += k64 * av.w;
  }
  int tgt = (c < 3) ? c : 3;
  float* dst = accb + tgt * HW + (yt * 4 + r) * 256 + x0;
  atomicAdd(dst + 0, a0); atomicAdd(dst + 1, a1);
  atomicAdd(dst + 2, a2); atomicAdd(dst + 3, a3);
}

// ---------------- K5: out = num / (den + muC), muC = sum_m (sum_u mu[u][m])^2 -----------
__global__ __launch_bounds__(256) void k_final(const float* __restrict__ accb,
                                               const float* __restrict__ mu,
                                               float* __restrict__ out){
  int pix = blockIdx.x * 256 + threadIdx.x;
  float muC = 0.f;
  #pragma unroll
  for (int m = 0; m < 10; ++m){
    float s = 0.f;
    for (int u = 0; u < 65; ++u) s += mu[u * 10 + m];
    muC += s * s;
  }
  float inv = 1.f / (accb[3 * HW + pix] + muC);
  #pragma unroll
  for (int cc = 0; cc < 3; ++cc) out[cc * HW + pix] = accb[cc * HW + pix] * inv;
}

__global__ void k_zero(float* __restrict__ p, int n){
  int i = blockIdx.x * blockDim.x + threadIdx.x;
  if (i < n) p[i] = 0.f;
}

extern "C" void kernel_launch(void* const* d_in, const int* in_sizes, int n_in,
                              void* d_out, int out_size, void* d_ws, size_t ws_size,
                              hipStream_t stream) {
  const float* img  = (const float*)d_in[0];
  const float* zern = (const float*)d_in[1];
  const float* w1   = (const float*)d_in[2];
  const float* b1   = (const float*)d_in[3];
  const float* w2   = (const float*)d_in[4];
  const float* b2   = (const float*)d_in[5];
  const float* w3   = (const float*)d_in[6];
  const float* b3   = (const float*)d_in[7];
  const float* bl   = (const float*)d_in[8];
  const float* br   = (const float*)d_in[9];
  const float* mu   = (const float*)d_in[10];
  float* out = (float*)d_out;

  float* w     = (float*)d_ws;
  float* tilt  = w;              // 3 * HW
  float* coefp = w + 3 * HW;     // 100 * HW
  float* vbuf  = w + 103 * HW;   // 110 * HW
  float* accb  = w + 213 * HW;   // 4 * HW

  k_gridsample<<<256, 256, 0, stream>>>(img, zern, tilt);
  k_mlp<<<2048, 256, 0, stream>>>(zern, w1, b1, w2, b2, w3, b3, coefp);
  k_zero<<<(4 * HW + 255) / 256, 256, 0, stream>>>(accb, 4 * HW);
  for (int c = 0; c < 4; ++c){
    int np = (c < 3) ? 110 : 100;
    k_vconv<<<np * 16, 256, 0, stream>>>(tilt, coefp, bl, mu, vbuf, c);
    int ng = (c < 3) ? 11 : 10;
    k_hconv<<<ng * 64, 256, 0, stream>>>(vbuf, br, mu, accb, c);
  }
  k_final<<<256, 256, 0, stream>>>(accb, mu, out);
}

// Round 2
// 1283.841 us; speedup vs baseline: 1.1161x; 1.1161x over previous
//
#include <hip/hip_runtime.h>

#define HW 65536

__device__ __forceinline__ int refl(int i){ if (i < 0) i = -i; if (i > 255) i = 510 - i; return i; }
__device__ __forceinline__ float lrelu(float x){ return x > 0.f ? x : 0.01f * x; }

// ---------------- K1: bilinear grid sample (border, align_corners=False) ----------------
__global__ __launch_bounds__(256) void k_gridsample(const float* __restrict__ img,
                                                    const float* __restrict__ zern,
                                                    float* __restrict__ tilt){
  int x = threadIdx.x, y = blockIdx.x;
  int pix = y * 256 + x;
  float px = zern[pix * 35 + 0], py = zern[pix * 35 + 1];
  float ix = ((float)x + px) * (256.f / 255.f) - 0.5f;
  float iy = ((float)y + py) * (256.f / 255.f) - 0.5f;
  ix = fminf(fmaxf(ix, 0.f), 255.f);
  iy = fminf(fmaxf(iy, 0.f), 255.f);
  float x0f = floorf(ix), y0f = floorf(iy);
  float wx = ix - x0f, wy = iy - y0f;
  int x0 = (int)x0f, y0 = (int)y0f;
  int x1 = min(x0 + 1, 255), y1 = min(y0 + 1, 255);
  #pragma unroll
  for (int c = 0; c < 3; ++c){
    const float* im = img + c * HW;
    float g00 = im[y0 * 256 + x0], g01 = im[y0 * 256 + x1];
    float g10 = im[y1 * 256 + x0], g11 = im[y1 * 256 + x1];
    float top = g00 * (1.f - wx) + g01 * wx;
    float bot = g10 * (1.f - wx) + g11 * wx;
    tilt[c * HW + pix] = top * (1.f - wy) + bot * wy;
  }
}

// ---------------- MLP: thread-per-pixel, activations in VGPRs, weights via s_load -------
// Layer 1: 33 -> 200 (leaky relu). Writes ht planes [0,200).
__global__ __launch_bounds__(64, 1) void k_fc1(const float* __restrict__ zern,
    const float* __restrict__ w1, const float* __restrict__ b1,
    float* __restrict__ ht){
  int pix = blockIdx.x * 64 + threadIdx.x;
  float f[33];
  #pragma unroll
  for (int k = 0; k < 33; ++k) f[k] = zern[pix * 35 + 2 + k];
  for (int o = 0; o < 200; o += 2){
    float a0 = b1[o], a1 = b1[o + 1];
    #pragma unroll
    for (int k = 0; k < 33; ++k){
      a0 = fmaf(f[k], w1[o * 33 + k],      a0);
      a1 = fmaf(f[k], w1[o * 33 + 33 + k], a1);
    }
    ht[o * HW + pix]       = lrelu(a0);
    ht[(o + 1) * HW + pix] = lrelu(a1);
  }
}

// Layer 2: 200 -> 200 (leaky relu), IN-PLACE on ht (thread reads its whole column first).
__global__ __launch_bounds__(64, 1) void k_fc2(float* __restrict__ ht,
    const float* __restrict__ w2, const float* __restrict__ b2){
  int pix = blockIdx.x * 64 + threadIdx.x;
  float h[200];
  #pragma unroll
  for (int k = 0; k < 200; ++k) h[k] = ht[k * HW + pix];
  for (int o = 0; o < 200; o += 2){
    float a0 = b2[o], a1 = b2[o + 1];
    #pragma unroll
    for (int k = 0; k < 200; ++k){
      a0 = fmaf(h[k], w2[o * 200 + k],       a0);
      a1 = fmaf(h[k], w2[o * 200 + 200 + k], a1);
    }
    ht[o * HW + pix]       = lrelu(a0);
    ht[(o + 1) * HW + pix] = lrelu(a1);
  }
}

// Layer 3: 200 -> 100 (no act). Reads ht planes [0,200) to regs, writes coef planes [0,100).
__global__ __launch_bounds__(64, 1) void k_fc3(float* __restrict__ ht,
    const float* __restrict__ w3, const float* __restrict__ b3){
  int pix = blockIdx.x * 64 + threadIdx.x;
  float h[200];
  #pragma unroll
  for (int k = 0; k < 200; ++k) h[k] = ht[k * HW + pix];
  for (int o = 0; o < 100; o += 2){
    float a0 = b3[o], a1 = b3[o + 1];
    #pragma unroll
    for (int k = 0; k < 200; ++k){
      a0 = fmaf(h[k], w3[o * 200 + k],       a0);
      a1 = fmaf(h[k], w3[o * 200 + 200 + k], a1);
    }
    ht[o * HW + pix]       = a0;
    ht[(o + 1) * HW + pix] = a1;
  }
}

// ---------------- K3: vertical 65-tap conv (reflect), per channel-class c ----------------
__global__ __launch_bounds__(256) void k_vconv(const float* __restrict__ tilt,
    const float* __restrict__ coefp, const float* __restrict__ bl,
    const float* __restrict__ mu, float* __restrict__ vbuf, int c){
  __shared__ float sx[128][97];
  __shared__ float sL[65];
  int tid = threadIdx.x;
  int q  = blockIdx.x >> 4;
  int ti = blockIdx.x & 15;
  int yt = ti >> 1, xt = ti & 1;
  int x0g = xt * 128;
  int ybase = yt * 32 - 32;
  if (tid < 65){
    float kv;
    if (c == 3 || q < 100) kv = bl[tid * 10 + q / 10];
    else                   kv = mu[tid * 10 + (q - 100)];
    sL[tid] = kv;
  }
  const float* tc = tilt + c * HW;
  const float* cq = coefp + q * HW;
  for (int e = tid; e < 96 * 128; e += 256){
    int yy = e >> 7, cxx = e & 127;
    int yin = refl(ybase + yy);
    int g = yin * 256 + x0g + cxx;
    float v;
    if (c < 3){ v = tc[g]; if (q < 100) v *= cq[g]; }
    else        v = cq[g];
    sx[cxx][yy] = v;
  }
  __syncthreads();
  int cx = tid & 127, ys = tid >> 7;
  int yb = ys * 16;
  float acc[16];
  #pragma unroll
  for (int t = 0; t < 16; ++t) acc[t] = 0.f;
  for (int u = 0; u < 64; u += 4){
    float w[20];
    #pragma unroll
    for (int r2 = 0; r2 < 20; ++r2) w[r2] = sx[cx][yb + u + r2];
    float k0 = sL[u], k1 = sL[u + 1], k2 = sL[u + 2], k3 = sL[u + 3];
    #pragma unroll
    for (int t = 0; t < 16; ++t)
      acc[t] += k0 * w[t] + k1 * w[t + 1] + k2 * w[t + 2] + k3 * w[t + 3];
  }
  float k64 = sL[64];
  #pragma unroll
  for (int t = 0; t < 16; ++t) acc[t] += k64 * sx[cx][yb + 64 + t];
  int yo = yt * 32 + yb;
  #pragma unroll
  for (int t = 0; t < 16; ++t)
    vbuf[q * HW + (yo + t) * 256 + x0g + cx] = acc[t];
}

// ---------------- K4: horizontal 65-tap conv (reflect) + accumulate over planes ---------
__global__ __launch_bounds__(256) void k_hconv(const float* __restrict__ vbuf,
    const float* __restrict__ br, const float* __restrict__ mu,
    float* __restrict__ accb, int c){
  __shared__ __align__(16) float sr[4][320];
  __shared__ float sR[65];
  int tid = threadIdx.x;
  int g  = blockIdx.x >> 6;
  int yt = blockIdx.x & 63;
  int r = tid >> 6, xg = tid & 63, x0 = xg * 4;
  float a0 = 0.f, a1 = 0.f, a2 = 0.f, a3 = 0.f;
  for (int bb = 0; bb < 10; ++bb){
    int q; const float* kp;
    if (c < 3){
      if (g < 10){ q = g * 10 + bb; kp = br; }
      else        { q = 100 + bb;    kp = mu; }
    } else        { q = g * 10 + bb; kp = br; }
    __syncthreads();
    if (tid < 65) sR[tid] = kp[tid * 10 + bb];
    for (int e = tid; e < 4 * 320; e += 256){
      int rr = e / 320, i = e - rr * 320;
      int xin = refl(i - 32);
      sr[rr][i] = vbuf[q * HW + (yt * 4 + rr) * 256 + xin];
    }
    __syncthreads();
    float4 av = *(const float4*)&sr[r][x0];
    for (int u = 0; u < 64; u += 4){
      float4 bv = *(const float4*)&sr[r][x0 + u + 4];
      float k0 = sR[u], k1 = sR[u + 1], k2 = sR[u + 2], k3 = sR[u + 3];
      a0 += k0 * av.x + k1 * av.y + k2 * av.z + k3 * av.w;
      a1 += k0 * av.y + k1 * av.z + k2 * av.w + k3 * bv.x;
      a2 += k0 * av.z + k1 * av.w + k2 * bv.x + k3 * bv.y;
      a3 += k0 * av.w + k1 * bv.x + k2 * bv.y + k3 * bv.z;
      av = bv;
    }
    float k64 = sR[64];
    a0 += k64 * av.x; a1 += k64 * av.y; a2 += k64 * av.z; a3 += k64 * av.w;
  }
  int tgt = (c < 3) ? c : 3;
  float* dst = accb + tgt * HW + (yt * 4 + r) * 256 + x0;
  atomicAdd(dst + 0, a0); atomicAdd(dst + 1, a1);
  atomicAdd(dst + 2, a2); atomicAdd(dst + 3, a3);
}

// ---------------- K5: out = num / (den + muC), muC = sum_m (sum_u mu[u][m])^2 -----------
__global__ __launch_bounds__(256) void k_final(const float* __restrict__ accb,
                                               const float* __restrict__ mu,
                                               float* __restrict__ out){
  int pix = blockIdx.x * 256 + threadIdx.x;
  float muC = 0.f;
  #pragma unroll
  for (int m = 0; m < 10; ++m){
    float s = 0.f;
    for (int u = 0; u < 65; ++u) s += mu[u * 10 + m];
    muC += s * s;
  }
  float inv = 1.f / (accb[3 * HW + pix] + muC);
  #pragma unroll
  for (int cc = 0; cc < 3; ++cc) out[cc * HW + pix] = accb[cc * HW + pix] * inv;
}

__global__ void k_zero(float* __restrict__ p, int n){
  int i = blockIdx.x * blockDim.x + threadIdx.x;
  if (i < n) p[i] = 0.f;
}

extern "C" void kernel_launch(void* const* d_in, const int* in_sizes, int n_in,
                              void* d_out, int out_size, void* d_ws, size_t ws_size,
                              hipStream_t stream) {
  const float* img  = (const float*)d_in[0];
  const float* zern = (const float*)d_in[1];
  const float* w1   = (const float*)d_in[2];
  const float* b1   = (const float*)d_in[3];
  const float* w2   = (const float*)d_in[4];
  const float* b2   = (const float*)d_in[5];
  const float* w3   = (const float*)d_in[6];
  const float* b3   = (const float*)d_in[7];
  const float* bl   = (const float*)d_in[8];
  const float* br   = (const float*)d_in[9];
  const float* mu   = (const float*)d_in[10];
  float* out = (float*)d_out;

  float* w     = (float*)d_ws;
  float* tilt  = w;              // planes [0,3)
  float* ht    = w + 3 * HW;     // planes [3,203): h1 -> h2 (in-place) -> coef in [3,103)
  float* coefp = w + 3 * HW;     // planes [3,103)  (first 100 planes of ht region)
  float* vbuf  = w + 103 * HW;   // planes [103,213)
  float* accb  = w + 213 * HW;   // planes [213,217)

  k_gridsample<<<256, 256, 0, stream>>>(img, zern, tilt);
  k_fc1<<<1024, 64, 0, stream>>>(zern, w1, b1, ht);
  k_fc2<<<1024, 64, 0, stream>>>(ht, w2, b2);
  k_fc3<<<1024, 64, 0, stream>>>(ht, w3, b3);
  k_zero<<<(4 * HW + 255) / 256, 256, 0, stream>>>(accb, 4 * HW);
  for (int c = 0; c < 4; ++c){
    int np = (c < 3) ? 110 : 100;
    k_vconv<<<np * 16, 256, 0, stream>>>(tilt, coefp, bl, mu, vbuf, c);
    int ng = (c < 3) ? 11 : 10;
    k_hconv<<<ng * 64, 256, 0, stream>>>(vbuf, br, mu, accb, c);
  }
  k_final<<<256, 256, 0, stream>>>(accb, mu, out);
}

// Round 3
// 531.227 us; speedup vs baseline: 2.6973x; 2.4167x over previous
//
#include <hip/hip_runtime.h>

#define HW 65536

typedef __attribute__((ext_vector_type(8))) short short8;
typedef __attribute__((ext_vector_type(4))) float float4v;

__device__ __forceinline__ int refl(int i){ if (i < 0) i = -i; if (i > 255) i = 510 - i; return i; }
__device__ __forceinline__ float lrelu(float x){ return x > 0.f ? x : 0.01f * x; }
__device__ __forceinline__ unsigned short f2bf(float x){
  union { float f; unsigned int u; } v; v.f = x;
  unsigned int r = v.u + 0x7fff + ((v.u >> 16) & 1);
  return (unsigned short)(r >> 16);
}

// ---------------- K1: bilinear grid sample (border, align_corners=False) ----------------
__global__ __launch_bounds__(256) void k_gridsample(const float* __restrict__ img,
                                                    const float* __restrict__ zern,
                                                    float* __restrict__ tilt){
  int x = threadIdx.x, y = blockIdx.x;
  int pix = y * 256 + x;
  float px = zern[pix * 35 + 0], py = zern[pix * 35 + 1];
  float ix = ((float)x + px) * (256.f / 255.f) - 0.5f;
  float iy = ((float)y + py) * (256.f / 255.f) - 0.5f;
  ix = fminf(fmaxf(ix, 0.f), 255.f);
  iy = fminf(fmaxf(iy, 0.f), 255.f);
  float x0f = floorf(ix), y0f = floorf(iy);
  float wx = ix - x0f, wy = iy - y0f;
  int x0 = (int)x0f, y0 = (int)y0f;
  int x1 = min(x0 + 1, 255), y1 = min(y0 + 1, 255);
  #pragma unroll
  for (int c = 0; c < 3; ++c){
    const float* im = img + c * HW;
    float g00 = im[y0 * 256 + x0], g01 = im[y0 * 256 + x1];
    float g10 = im[y1 * 256 + x0], g11 = im[y1 * 256 + x1];
    float top = g00 * (1.f - wx) + g01 * wx;
    float bot = g10 * (1.f - wx) + g11 * wx;
    tilt[c * HW + pix] = top * (1.f - wy) + bot * wy;
  }
}

// ---------------- Weight convert: fp32 -> zero-padded bf16 ------------------------------
// w1p: 208x64 @0 ; w2p: 208x224 @13312 ; w3p: 112x224 @59904. Total 84992 shorts.
#define W2OFF 13312
#define W3OFF 59904
__global__ __launch_bounds__(256) void k_wcvt(const float* __restrict__ w1,
    const float* __restrict__ w2, const float* __restrict__ w3,
    unsigned short* __restrict__ wbf){
  int i = blockIdx.x * 256 + threadIdx.x;
  if (i < 208 * 64){
    int n = i >> 6, k = i & 63;
    float v = (n < 200 && k < 33) ? w1[n * 33 + k] : 0.f;
    wbf[i] = f2bf(v);
  } else if (i < W2OFF + 208 * 224){
    int j = i - W2OFF; int n = j / 224, k = j - n * 224;
    float v = (n < 200 && k < 200) ? w2[n * 200 + k] : 0.f;
    wbf[i] = f2bf(v);
  } else if (i < 84992){
    int j = i - W3OFF; int n = j / 224, k = j - n * 224;
    float v = (n < 100 && k < 200) ? w3[n * 200 + k] : 0.f;
    wbf[i] = f2bf(v);
  }
}

// ---------------- Fused MLP: 64-pixel tile, 3 layers, MFMA bf16 -------------------------
// LDS: region A [0,29696) = H1 (64x232 bf16), later H3 (64x113 f32)
//      region B [29696,59392) = X (64x72 bf16) at start, later H2 (64x232 bf16)
#define HSTR 232
__global__ __launch_bounds__(256, 1) void k_mlp(const float* __restrict__ zern,
    const float* __restrict__ b1f, const float* __restrict__ b2f,
    const float* __restrict__ b3f, const unsigned short* __restrict__ wbf,
    float* __restrict__ coefp){
  __shared__ char smem[59392];
  unsigned short* H1 = (unsigned short*)smem;
  float*          H3 = (float*)smem;
  unsigned short* XB = (unsigned short*)(smem + 29696);
  unsigned short* H2 = XB;
  int tid = threadIdx.x;
  int pix0 = blockIdx.x * 64;
  int lane = tid & 63, wv = tid >> 6;
  int ln = lane & 15, qd = lane >> 4;

  // zero X region + H1 tail cols [208,232)
  for (int e = tid; e < 2304; e += 256) ((int*)XB)[e] = 0;
  for (int e = tid; e < 768; e += 256){
    int m = e / 12, j = e - m * 12;
    ((int*)H1)[m * 116 + 104 + j] = 0;
  }
  __syncthreads();
  // fill X: bf16 of zern[...,2+k]
  for (int e = tid; e < 64 * 33; e += 256){
    int m = e / 33, k = e - m * 33;
    XB[m * 72 + k] = f2bf(zern[(pix0 + m) * 35 + 2 + k]);
  }
  __syncthreads();

  // ---- layer 1: X(64x64) x W1^T(208x64) -> H1 ----
  for (int nt = wv; nt < 13; nt += 4){
    int n = nt * 16 + ln;
    short8 b0 = *(const short8*)(wbf + n * 64 + qd * 8);
    short8 b1 = *(const short8*)(wbf + n * 64 + 32 + qd * 8);
    float bv = (n < 200) ? b1f[n] : 0.f;
    #pragma unroll
    for (int mt = 0; mt < 4; ++mt){
      float4v acc = {bv, bv, bv, bv};
      short8 a0 = *(const short8*)(XB + (mt * 16 + ln) * 72 + qd * 8);
      short8 a1 = *(const short8*)(XB + (mt * 16 + ln) * 72 + 32 + qd * 8);
      acc = __builtin_amdgcn_mfma_f32_16x16x32_bf16(a0, b0, acc, 0, 0, 0);
      acc = __builtin_amdgcn_mfma_f32_16x16x32_bf16(a1, b1, acc, 0, 0, 0);
      #pragma unroll
      for (int r = 0; r < 4; ++r)
        H1[(mt * 16 + qd * 4 + r) * HSTR + n] = f2bf(lrelu(acc[r]));
    }
  }
  __syncthreads();

  // ---- layer 2: H1 x W2^T(208x224) -> H2 ; also zero H2 tail cols ----
  for (int e = tid; e < 768; e += 256){
    int m = e / 12, j = e - m * 12;
    ((int*)H2)[m * 116 + 104 + j] = 0;
  }
  {
    const unsigned short* w2p = wbf + W2OFF;
    for (int nt = wv; nt < 13; nt += 4){
      int n = nt * 16 + ln;
      short8 bf[7];
      #pragma unroll
      for (int kc = 0; kc < 7; ++kc)
        bf[kc] = *(const short8*)(w2p + n * 224 + kc * 32 + qd * 8);
      float bv = (n < 200) ? b2f[n] : 0.f;
      #pragma unroll
      for (int mt = 0; mt < 4; ++mt){
        float4v acc = {bv, bv, bv, bv};
        #pragma unroll
        for (int kc = 0; kc < 7; ++kc){
          short8 af = *(const short8*)(H1 + (mt * 16 + ln) * HSTR + kc * 32 + qd * 8);
          acc = __builtin_amdgcn_mfma_f32_16x16x32_bf16(af, bf[kc], acc, 0, 0, 0);
        }
        #pragma unroll
        for (int r = 0; r < 4; ++r)
          H2[(mt * 16 + qd * 4 + r) * HSTR + n] = f2bf(lrelu(acc[r]));
      }
    }
  }
  __syncthreads();

  // ---- layer 3: H2 x W3^T(112x224) -> H3 (f32, stride 113) ----
  {
    const unsigned short* w3p = wbf + W3OFF;
    for (int nt = wv; nt < 7; nt += 4){
      int n = nt * 16 + ln;
      short8 bf[7];
      #pragma unroll
      for (int kc = 0; kc < 7; ++kc)
        bf[kc] = *(const short8*)(w3p + n * 224 + kc * 32 + qd * 8);
      float bv = (n < 100) ? b3f[n] : 0.f;
      #pragma unroll
      for (int mt = 0; mt < 4; ++mt){
        float4v acc = {bv, bv, bv, bv};
        #pragma unroll
        for (int kc = 0; kc < 7; ++kc){
          short8 af = *(const short8*)(H2 + (mt * 16 + ln) * HSTR + kc * 32 + qd * 8);
          acc = __builtin_amdgcn_mfma_f32_16x16x32_bf16(af, bf[kc], acc, 0, 0, 0);
        }
        #pragma unroll
        for (int r = 0; r < 4; ++r)
          H3[(mt * 16 + qd * 4 + r) * 113 + n] = acc[r];
      }
    }
  }
  __syncthreads();

  // ---- epilogue: coalesced store of coef planes ----
  for (int e = tid; e < 100 * 64; e += 256){
    int n = e >> 6, m = e & 63;
    coefp[n * HW + pix0 + m] = H3[m * 113 + n];
  }
}

// ---------------- K3: vertical 65-tap conv (reflect), per channel-class c ----------------
__global__ __launch_bounds__(256) void k_vconv(const float* __restrict__ tilt,
    const float* __restrict__ coefp, const float* __restrict__ bl,
    const float* __restrict__ mu, float* __restrict__ vbuf, int c){
  __shared__ float sx[128][97];
  __shared__ float sL[65];
  int tid = threadIdx.x;
  int q  = blockIdx.x >> 4;
  int ti = blockIdx.x & 15;
  int yt = ti >> 1, xt = ti & 1;
  int x0g = xt * 128;
  int ybase = yt * 32 - 32;
  if (tid < 65){
    float kv;
    if (c == 3 || q < 100) kv = bl[tid * 10 + q / 10];
    else                   kv = mu[tid * 10 + (q - 100)];
    sL[tid] = kv;
  }
  const float* tc = tilt + c * HW;
  const float* cq = coefp + q * HW;
  for (int e = tid; e < 96 * 128; e += 256){
    int yy = e >> 7, cxx = e & 127;
    int yin = refl(ybase + yy);
    int g = yin * 256 + x0g + cxx;
    float v;
    if (c < 3){ v = tc[g]; if (q < 100) v *= cq[g]; }
    else        v = cq[g];
    sx[cxx][yy] = v;
  }
  __syncthreads();
  int cx = tid & 127, ys = tid >> 7;
  int yb = ys * 16;
  float acc[16];
  #pragma unroll
  for (int t = 0; t < 16; ++t) acc[t] = 0.f;
  for (int u = 0; u < 64; u += 4){
    float w[20];
    #pragma unroll
    for (int r2 = 0; r2 < 20; ++r2) w[r2] = sx[cx][yb + u + r2];
    float k0 = sL[u], k1 = sL[u + 1], k2 = sL[u + 2], k3 = sL[u + 3];
    #pragma unroll
    for (int t = 0; t < 16; ++t)
      acc[t] += k0 * w[t] + k1 * w[t + 1] + k2 * w[t + 2] + k3 * w[t + 3];
  }
  float k64 = sL[64];
  #pragma unroll
  for (int t = 0; t < 16; ++t) acc[t] += k64 * sx[cx][yb + 64 + t];
  int yo = yt * 32 + yb;
  #pragma unroll
  for (int t = 0; t < 16; ++t)
    vbuf[q * HW + (yo + t) * 256 + x0g + cx] = acc[t];
}

// ---------------- K4: horizontal 65-tap conv (reflect) + accumulate over planes ---------
__global__ __launch_bounds__(256) void k_hconv(const float* __restrict__ vbuf,
    const float* __restrict__ br, const float* __restrict__ mu,
    float* __restrict__ accb, int c){
  __shared__ __align__(16) float sr[4][320];
  __shared__ float sR[65];
  int tid = threadIdx.x;
  int g  = blockIdx.x >> 6;
  int yt = blockIdx.x & 63;
  int r = tid >> 6, xg = tid & 63, x0 = xg * 4;
  float a0 = 0.f, a1 = 0.f, a2 = 0.f, a3 = 0.f;
  for (int bb = 0; bb < 10; ++bb){
    int q; const float* kp;
    if (c < 3){
      if (g < 10){ q = g * 10 + bb; kp = br; }
      else        { q = 100 + bb;    kp = mu; }
    } else        { q = g * 10 + bb; kp = br; }
    __syncthreads();
    if (tid < 65) sR[tid] = kp[tid * 10 + bb];
    for (int e = tid; e < 4 * 320; e += 256){
      int rr = e / 320, i = e - rr * 320;
      int xin = refl(i - 32);
      sr[rr][i] = vbuf[q * HW + (yt * 4 + rr) * 256 + xin];
    }
    __syncthreads();
    float4 av = *(const float4*)&sr[r][x0];
    for (int u = 0; u < 64; u += 4){
      float4 bv = *(const float4*)&sr[r][x0 + u + 4];
      float k0 = sR[u], k1 = sR[u + 1], k2 = sR[u + 2], k3 = sR[u + 3];
      a0 += k0 * av.x + k1 * av.y + k2 * av.z + k3 * av.w;
      a1 += k0 * av.y + k1 * av.z + k2 * av.w + k3 * bv.x;
      a2 += k0 * av.z + k1 * av.w + k2 * bv.x + k3 * bv.y;
      a3 += k0 * av.w + k1 * bv.x + k2 * bv.y + k3 * bv.z;
      av = bv;
    }
    float k64 = sR[64];
    a0 += k64 * av.x; a1 += k64 * av.y; a2 += k64 * av.z; a3 += k64 * av.w;
  }
  int tgt = (c < 3) ? c : 3;
  float* dst = accb + tgt * HW + (yt * 4 + r) * 256 + x0;
  atomicAdd(dst + 0, a0); atomicAdd(dst + 1, a1);
  atomicAdd(dst + 2, a2); atomicAdd(dst + 3, a3);
}

// ---------------- K5: out = num / (den + muC) -------------------------------------------
__global__ __launch_bounds__(256) void k_final(const float* __restrict__ accb,
                                               const float* __restrict__ mu,
                                               float* __restrict__ out){
  int pix = blockIdx.x * 256 + threadIdx.x;
  float muC = 0.f;
  #pragma unroll
  for (int m = 0; m < 10; ++m){
    float s = 0.f;
    for (int u = 0; u < 65; ++u) s += mu[u * 10 + m];
    muC += s * s;
  }
  float inv = 1.f / (accb[3 * HW + pix] + muC);
  #pragma unroll
  for (int cc = 0; cc < 3; ++cc) out[cc * HW + pix] = accb[cc * HW + pix] * inv;
}

__global__ void k_zero(float* __restrict__ p, int n){
  int i = blockIdx.x * blockDim.x + threadIdx.x;
  if (i < n) p[i] = 0.f;
}

extern "C" void kernel_launch(void* const* d_in, const int* in_sizes, int n_in,
                              void* d_out, int out_size, void* d_ws, size_t ws_size,
                              hipStream_t stream) {
  const float* img  = (const float*)d_in[0];
  const float* zern = (const float*)d_in[1];
  const float* w1   = (const float*)d_in[2];
  const float* b1   = (const float*)d_in[3];
  const float* w2   = (const float*)d_in[4];
  const float* b2   = (const float*)d_in[5];
  const float* w3   = (const float*)d_in[6];
  const float* b3   = (const float*)d_in[7];
  const float* bl   = (const float*)d_in[8];
  const float* br   = (const float*)d_in[9];
  const float* mu   = (const float*)d_in[10];
  float* out = (float*)d_out;

  float* w     = (float*)d_ws;
  float* tilt  = w;              // planes [0,3)
  float* coefp = w + 3 * HW;     // planes [3,103)
  float* vbuf  = w + 103 * HW;   // planes [103,213)
  float* accb  = w + 213 * HW;   // planes [213,217)
  unsigned short* wbf = (unsigned short*)vbuf; // bf16 weights, dead before vconv writes

  k_gridsample<<<256, 256, 0, stream>>>(img, zern, tilt);
  k_wcvt<<<332, 256, 0, stream>>>(w1, w2, w3, wbf);
  k_mlp<<<1024, 256, 0, stream>>>(zern, b1, b2, b3, wbf, coefp);
  k_zero<<<(4 * HW + 255) / 256, 256, 0, stream>>>(accb, 4 * HW);
  for (int c = 0; c < 4; ++c){
    int np = (c < 3) ? 110 : 100;
    k_vconv<<<np * 16, 256, 0, stream>>>(tilt, coefp, bl, mu, vbuf, c);
    int ng = (c < 3) ? 11 : 10;
    k_hconv<<<ng * 64, 256, 0, stream>>>(vbuf, br, mu, accb, c);
  }
  k_final<<<256, 256, 0, stream>>>(accb, mu, out);
}

// Round 4
// 253.154 us; speedup vs baseline: 5.6602x; 2.0984x over previous
//
#include <hip/hip_runtime.h>

#define HW 65536

typedef __attribute__((ext_vector_type(8))) short short8;
typedef __attribute__((ext_vector_type(4))) float float4v;

__device__ __forceinline__ int refl(int i){ if (i < 0) i = -i; if (i > 255) i = 510 - i; return i; }
__device__ __forceinline__ float lrelu(float x){ return x > 0.f ? x : 0.01f * x; }
__device__ __forceinline__ unsigned short f2bf(float x){
  union { float f; unsigned int u; } v; v.f = x;
  unsigned int r = v.u + 0x7fff + ((v.u >> 16) & 1);
  return (unsigned short)(r >> 16);
}

// ---------------- K1: bilinear grid sample (border, align_corners=False) ----------------
__global__ __launch_bounds__(256) void k_gridsample(const float* __restrict__ img,
                                                    const float* __restrict__ zern,
                                                    float* __restrict__ tilt){
  int x = threadIdx.x, y = blockIdx.x;
  int pix = y * 256 + x;
  float px = zern[pix * 35 + 0], py = zern[pix * 35 + 1];
  float ix = ((float)x + px) * (256.f / 255.f) - 0.5f;
  float iy = ((float)y + py) * (256.f / 255.f) - 0.5f;
  ix = fminf(fmaxf(ix, 0.f), 255.f);
  iy = fminf(fmaxf(iy, 0.f), 255.f);
  float x0f = floorf(ix), y0f = floorf(iy);
  float wx = ix - x0f, wy = iy - y0f;
  int x0 = (int)x0f, y0 = (int)y0f;
  int x1 = min(x0 + 1, 255), y1 = min(y0 + 1, 255);
  #pragma unroll
  for (int c = 0; c < 3; ++c){
    const float* im = img + c * HW;
    float g00 = im[y0 * 256 + x0], g01 = im[y0 * 256 + x1];
    float g10 = im[y1 * 256 + x0], g11 = im[y1 * 256 + x1];
    float top = g00 * (1.f - wx) + g01 * wx;
    float bot = g10 * (1.f - wx) + g11 * wx;
    tilt[c * HW + pix] = top * (1.f - wy) + bot * wy;
  }
}

// ---------------- Weight convert: fp32 -> zero-padded bf16 ------------------------------
#define W2OFF 13312
#define W3OFF 59904
__global__ __launch_bounds__(256) void k_wcvt(const float* __restrict__ w1,
    const float* __restrict__ w2, const float* __restrict__ w3,
    unsigned short* __restrict__ wbf){
  int i = blockIdx.x * 256 + threadIdx.x;
  if (i < 208 * 64){
    int n = i >> 6, k = i & 63;
    float v = (n < 200 && k < 33) ? w1[n * 33 + k] : 0.f;
    wbf[i] = f2bf(v);
  } else if (i < W2OFF + 208 * 224){
    int j = i - W2OFF; int n = j / 224, k = j - n * 224;
    float v = (n < 200 && k < 200) ? w2[n * 200 + k] : 0.f;
    wbf[i] = f2bf(v);
  } else if (i < 84992){
    int j = i - W3OFF; int n = j / 224, k = j - n * 224;
    float v = (n < 100 && k < 200) ? w3[n * 200 + k] : 0.f;
    wbf[i] = f2bf(v);
  }
}

// ---------------- Fused MLP: 64-pixel tile, 3 layers, MFMA bf16 -------------------------
#define HSTR 232
__global__ __launch_bounds__(256, 1) void k_mlp(const float* __restrict__ zern,
    const float* __restrict__ b1f, const float* __restrict__ b2f,
    const float* __restrict__ b3f, const unsigned short* __restrict__ wbf,
    float* __restrict__ coefp){
  __shared__ char smem[59392];
  unsigned short* H1 = (unsigned short*)smem;
  float*          H3 = (float*)smem;
  unsigned short* XB = (unsigned short*)(smem + 29696);
  unsigned short* H2 = XB;
  int tid = threadIdx.x;
  int pix0 = blockIdx.x * 64;
  int lane = tid & 63, wv = tid >> 6;
  int ln = lane & 15, qd = lane >> 4;

  for (int e = tid; e < 2304; e += 256) ((int*)XB)[e] = 0;
  for (int e = tid; e < 768; e += 256){
    int m = e / 12, j = e - m * 12;
    ((int*)H1)[m * 116 + 104 + j] = 0;
  }
  __syncthreads();
  for (int e = tid; e < 64 * 33; e += 256){
    int m = e / 33, k = e - m * 33;
    XB[m * 72 + k] = f2bf(zern[(pix0 + m) * 35 + 2 + k]);
  }
  __syncthreads();

  // ---- layer 1 ----
  for (int nt = wv; nt < 13; nt += 4){
    int n = nt * 16 + ln;
    short8 b0 = *(const short8*)(wbf + n * 64 + qd * 8);
    short8 b1 = *(const short8*)(wbf + n * 64 + 32 + qd * 8);
    float bv = (n < 200) ? b1f[n] : 0.f;
    #pragma unroll
    for (int mt = 0; mt < 4; ++mt){
      float4v acc = {bv, bv, bv, bv};
      short8 a0 = *(const short8*)(XB + (mt * 16 + ln) * 72 + qd * 8);
      short8 a1 = *(const short8*)(XB + (mt * 16 + ln) * 72 + 32 + qd * 8);
      acc = __builtin_amdgcn_mfma_f32_16x16x32_bf16(a0, b0, acc, 0, 0, 0);
      acc = __builtin_amdgcn_mfma_f32_16x16x32_bf16(a1, b1, acc, 0, 0, 0);
      #pragma unroll
      for (int r = 0; r < 4; ++r)
        H1[(mt * 16 + qd * 4 + r) * HSTR + n] = f2bf(lrelu(acc[r]));
    }
  }
  __syncthreads();

  // ---- layer 2 ----
  for (int e = tid; e < 768; e += 256){
    int m = e / 12, j = e - m * 12;
    ((int*)H2)[m * 116 + 104 + j] = 0;
  }
  {
    const unsigned short* w2p = wbf + W2OFF;
    for (int nt = wv; nt < 13; nt += 4){
      int n = nt * 16 + ln;
      short8 bf[7];
      #pragma unroll
      for (int kc = 0; kc < 7; ++kc)
        bf[kc] = *(const short8*)(w2p + n * 224 + kc * 32 + qd * 8);
      float bv = (n < 200) ? b2f[n] : 0.f;
      #pragma unroll
      for (int mt = 0; mt < 4; ++mt){
        float4v acc = {bv, bv, bv, bv};
        #pragma unroll
        for (int kc = 0; kc < 7; ++kc){
          short8 af = *(const short8*)(H1 + (mt * 16 + ln) * HSTR + kc * 32 + qd * 8);
          acc = __builtin_amdgcn_mfma_f32_16x16x32_bf16(af, bf[kc], acc, 0, 0, 0);
        }
        #pragma unroll
        for (int r = 0; r < 4; ++r)
          H2[(mt * 16 + qd * 4 + r) * HSTR + n] = f2bf(lrelu(acc[r]));
      }
    }
  }
  __syncthreads();

  // ---- layer 3 ----
  {
    const unsigned short* w3p = wbf + W3OFF;
    for (int nt = wv; nt < 7; nt += 4){
      int n = nt * 16 + ln;
      short8 bf[7];
      #pragma unroll
      for (int kc = 0; kc < 7; ++kc)
        bf[kc] = *(const short8*)(w3p + n * 224 + kc * 32 + qd * 8);
      float bv = (n < 100) ? b3f[n] : 0.f;
      #pragma unroll
      for (int mt = 0; mt < 4; ++mt){
        float4v acc = {bv, bv, bv, bv};
        #pragma unroll
        for (int kc = 0; kc < 7; ++kc){
          short8 af = *(const short8*)(H2 + (mt * 16 + ln) * HSTR + kc * 32 + qd * 8);
          acc = __builtin_amdgcn_mfma_f32_16x16x32_bf16(af, bf[kc], acc, 0, 0, 0);
        }
        #pragma unroll
        for (int r = 0; r < 4; ++r)
          H3[(mt * 16 + qd * 4 + r) * 113 + n] = acc[r];
      }
    }
  }
  __syncthreads();

  for (int e = tid; e < 100 * 64; e += 256){
    int n = e >> 6, m = e & 63;
    coefp[n * HW + pix0 + m] = H3[m * 113 + n];
  }
}

// ---------------- K3 v2: vertical conv, full-height 16-col strips, Sum_i in registers ---
// Blocks [0,640): (c in 0..3, j in 0..9, strip in 0..15): S_{c,j} = sum_i vconv(X_{c,i*10+j}, L_i)
// Blocks [640,688): (c in 0..2, strip): Smu_{c,m} = vconv(tilt_c, mu_m), m=0..9
__global__ __launch_bounds__(256) void k_vconv2(const float* __restrict__ tilt,
    const float* __restrict__ coefp, const float* __restrict__ bl,
    const float* __restrict__ mu, float* __restrict__ sbuf){
  __shared__ float sx[16 * 321];
  int tid = threadIdx.x;
  int bid = blockIdx.x;
  int tx = tid & 15, yg = tid >> 4;
  int yb = yg * 16;
  int t0 = tid >> 2, xq = tid & 3;

  if (bid < 640){
    int c = bid / 160;
    int rj = bid - c * 160;
    int j = rj >> 4;
    int s = rj & 15;
    int x0 = s * 16;
    const float* tc = tilt + c * HW;
    float4 treg[5];
    if (c < 3){
      #pragma unroll
      for (int k = 0; k < 5; ++k){
        int t = t0 + k * 64;
        int gy = refl(t - 32);
        treg[k] = *(const float4*)(tc + gy * 256 + x0 + xq * 4);
      }
    }
    float acc[16];
    #pragma unroll
    for (int r = 0; r < 16; ++r) acc[r] = 0.f;
    for (int i = 0; i < 10; ++i){
      const float* cq = coefp + (i * 10 + j) * HW;
      __syncthreads();
      #pragma unroll
      for (int k = 0; k < 5; ++k){
        int t = t0 + k * 64;
        int gy = refl(t - 32);
        float4 v = *(const float4*)(cq + gy * 256 + x0 + xq * 4);
        if (c < 3){ v.x *= treg[k].x; v.y *= treg[k].y; v.z *= treg[k].z; v.w *= treg[k].w; }
        int base = (xq * 4) * 321 + t;
        sx[base] = v.x; sx[base + 321] = v.y; sx[base + 642] = v.z; sx[base + 963] = v.w;
      }
      __syncthreads();
      for (int u = 0; u < 64; u += 4){
        float w[20];
        #pragma unroll
        for (int r = 0; r < 20; ++r) w[r] = sx[tx * 321 + yb + u + r];
        float k0 = bl[u * 10 + i],     k1 = bl[(u + 1) * 10 + i],
              k2 = bl[(u + 2) * 10 + i], k3 = bl[(u + 3) * 10 + i];
        #pragma unroll
        for (int r = 0; r < 16; ++r)
          acc[r] += k0 * w[r] + k1 * w[r + 1] + k2 * w[r + 2] + k3 * w[r + 3];
      }
      float k64 = bl[640 + i];
      #pragma unroll
      for (int r = 0; r < 16; ++r) acc[r] += k64 * sx[tx * 321 + yb + 64 + r];
    }
    float* S = sbuf + (c * 10 + j) * HW;
    #pragma unroll
    for (int r = 0; r < 16; ++r)
      S[(yb + r) * 256 + x0 + tx] = acc[r];
  } else {
    int b2 = bid - 640;
    int c = b2 >> 4;
    int s = b2 & 15;
    int x0 = s * 16;
    const float* tc = tilt + c * HW;
    #pragma unroll
    for (int k = 0; k < 5; ++k){
      int t = t0 + k * 64;
      int gy = refl(t - 32);
      float4 v = *(const float4*)(tc + gy * 256 + x0 + xq * 4);
      int base = (xq * 4) * 321 + t;
      sx[base] = v.x; sx[base + 321] = v.y; sx[base + 642] = v.z; sx[base + 963] = v.w;
    }
    __syncthreads();
    for (int m = 0; m < 10; ++m){
      float acc[16];
      #pragma unroll
      for (int r = 0; r < 16; ++r) acc[r] = 0.f;
      for (int u = 0; u < 64; u += 4){
        float w[20];
        #pragma unroll
        for (int r = 0; r < 20; ++r) w[r] = sx[tx * 321 + yb + u + r];
        float k0 = mu[u * 10 + m],     k1 = mu[(u + 1) * 10 + m],
              k2 = mu[(u + 2) * 10 + m], k3 = mu[(u + 3) * 10 + m];
        #pragma unroll
        for (int r = 0; r < 16; ++r)
          acc[r] += k0 * w[r] + k1 * w[r + 1] + k2 * w[r + 2] + k3 * w[r + 3];
      }
      float k64 = mu[640 + m];
      #pragma unroll
      for (int r = 0; r < 16; ++r) acc[r] += k64 * sx[tx * 321 + yb + 64 + r];
      float* S = sbuf + (40 + c * 10 + m) * HW;
      #pragma unroll
      for (int r = 0; r < 16; ++r)
        S[(yb + r) * 256 + x0 + tx] = acc[r];
    }
  }
}

// ---------------- K4 v2: horizontal conv over grouped planes, direct write --------------
// tgt<3: num_tgt = sum_j hconv(S_{tgt,j}, R_j) + sum_m hconv(Smu_{tgt,m}, mu_m)
// tgt=3: den     = sum_j hconv(S_{3,j},  R_j)
__global__ __launch_bounds__(256) void k_hconv2(const float* __restrict__ sbuf,
    const float* __restrict__ br, const float* __restrict__ mu,
    float* __restrict__ accb){
  __shared__ __align__(16) float sr[4][320];
  int tid = threadIdx.x;
  int tgt = blockIdx.x >> 6;
  int yt = blockIdx.x & 63;
  int r = tid >> 6, xg = tid & 63, x0 = xg * 4;
  int np = (tgt < 3) ? 20 : 10;
  float a0 = 0.f, a1 = 0.f, a2 = 0.f, a3 = 0.f;
  for (int p = 0; p < np; ++p){
    const float* plane; const float* kp; int col;
    if (tgt < 3){
      if (p < 10){ plane = sbuf + (tgt * 10 + p) * HW;        kp = br; col = p; }
      else        { plane = sbuf + (40 + tgt * 10 + p - 10) * HW; kp = mu; col = p - 10; }
    } else        { plane = sbuf + (30 + p) * HW;             kp = br; col = p; }
    __syncthreads();
    for (int e = tid; e < 1280; e += 256){
      int rr = e / 320, ii = e - rr * 320;
      sr[rr][ii] = plane[(yt * 4 + rr) * 256 + refl(ii - 32)];
    }
    __syncthreads();
    float4 av = *(const float4*)&sr[r][x0];
    for (int u = 0; u < 64; u += 4){
      float4 bv = *(const float4*)&sr[r][x0 + u + 4];
      float k0 = kp[u * 10 + col],       k1 = kp[(u + 1) * 10 + col],
            k2 = kp[(u + 2) * 10 + col], k3 = kp[(u + 3) * 10 + col];
      a0 += k0 * av.x + k1 * av.y + k2 * av.z + k3 * av.w;
      a1 += k0 * av.y + k1 * av.z + k2 * av.w + k3 * bv.x;
      a2 += k0 * av.z + k1 * av.w + k2 * bv.x + k3 * bv.y;
      a3 += k0 * av.w + k1 * bv.x + k2 * bv.y + k3 * bv.z;
      av = bv;
    }
    float k64 = kp[640 + col];
    a0 += k64 * av.x; a1 += k64 * av.y; a2 += k64 * av.z; a3 += k64 * av.w;
  }
  float4 res = {a0, a1, a2, a3};
  *(float4*)(accb + tgt * HW + (yt * 4 + r) * 256 + x0) = res;
}

// ---------------- K5: out = num / (den + muC) -------------------------------------------
__global__ __launch_bounds__(256) void k_final(const float* __restrict__ accb,
                                               const float* __restrict__ mu,
                                               float* __restrict__ out){
  int pix = blockIdx.x * 256 + threadIdx.x;
  float muC = 0.f;
  #pragma unroll
  for (int m = 0; m < 10; ++m){
    float s = 0.f;
    for (int u = 0; u < 65; ++u) s += mu[u * 10 + m];
    muC += s * s;
  }
  float inv = 1.f / (accb[3 * HW + pix] + muC);
  #pragma unroll
  for (int cc = 0; cc < 3; ++cc) out[cc * HW + pix] = accb[cc * HW + pix] * inv;
}

extern "C" void kernel_launch(void* const* d_in, const int* in_sizes, int n_in,
                              void* d_out, int out_size, void* d_ws, size_t ws_size,
                              hipStream_t stream) {
  const float* img  = (const float*)d_in[0];
  const float* zern = (const float*)d_in[1];
  const float* w1   = (const float*)d_in[2];
  const float* b1   = (const float*)d_in[3];
  const float* w2   = (const float*)d_in[4];
  const float* b2   = (const float*)d_in[5];
  const float* w3   = (const float*)d_in[6];
  const float* b3   = (const float*)d_in[7];
  const float* bl   = (const float*)d_in[8];
  const float* br   = (const float*)d_in[9];
  const float* mu   = (const float*)d_in[10];
  float* out = (float*)d_out;

  float* w     = (float*)d_ws;
  float* tilt  = w;              // planes [0,3)
  float* coefp = w + 3 * HW;     // planes [3,103)
  float* sbuf  = w + 103 * HW;   // planes [103,173): 40 S + 30 Smu
  float* accb  = w + 213 * HW;   // planes [213,217)
  unsigned short* wbf = (unsigned short*)sbuf; // bf16 weights, dead before vconv2 writes

  k_gridsample<<<256, 256, 0, stream>>>(img, zern, tilt);
  k_wcvt<<<332, 256, 0, stream>>>(w1, w2, w3, wbf);
  k_mlp<<<1024, 256, 0, stream>>>(zern, b1, b2, b3, wbf, coefp);
  k_vconv2<<<688, 256, 0, stream>>>(tilt, coefp, bl, mu, sbuf);
  k_hconv2<<<256, 256, 0, stream>>>(sbuf, br, mu, accb);
  k_final<<<256, 256, 0, stream>>>(accb, mu, out);
}

// Round 5
// 251.422 us; speedup vs baseline: 5.6992x; 1.0069x over previous
//
#include <hip/hip_runtime.h>

#define HW 65536

typedef __attribute__((ext_vector_type(8))) short short8;
typedef __attribute__((ext_vector_type(4))) float float4v;

__device__ __forceinline__ int refl(int i){ if (i < 0) i = -i; if (i > 255) i = 510 - i; return i; }
__device__ __forceinline__ float lrelu(float x){ return x > 0.f ? x : 0.01f * x; }
__device__ __forceinline__ unsigned short f2bf(float x){
  union { float f; unsigned int u; } v; v.f = x;
  unsigned int r = v.u + 0x7fff + ((v.u >> 16) & 1);
  return (unsigned short)(r >> 16);
}

// ---------------- K1: bilinear grid sample (border, align_corners=False) ----------------
__global__ __launch_bounds__(256) void k_gridsample(const float* __restrict__ img,
                                                    const float* __restrict__ zern,
                                                    float* __restrict__ tilt){
  int x = threadIdx.x, y = blockIdx.x;
  int pix = y * 256 + x;
  float px = zern[pix * 35 + 0], py = zern[pix * 35 + 1];
  float ix = ((float)x + px) * (256.f / 255.f) - 0.5f;
  float iy = ((float)y + py) * (256.f / 255.f) - 0.5f;
  ix = fminf(fmaxf(ix, 0.f), 255.f);
  iy = fminf(fmaxf(iy, 0.f), 255.f);
  float x0f = floorf(ix), y0f = floorf(iy);
  float wx = ix - x0f, wy = iy - y0f;
  int x0 = (int)x0f, y0 = (int)y0f;
  int x1 = min(x0 + 1, 255), y1 = min(y0 + 1, 255);
  #pragma unroll
  for (int c = 0; c < 3; ++c){
    const float* im = img + c * HW;
    float g00 = im[y0 * 256 + x0], g01 = im[y0 * 256 + x1];
    float g10 = im[y1 * 256 + x0], g11 = im[y1 * 256 + x1];
    float top = g00 * (1.f - wx) + g01 * wx;
    float bot = g10 * (1.f - wx) + g11 * wx;
    tilt[c * HW + pix] = top * (1.f - wy) + bot * wy;
  }
}

// ---------------- Weight convert: fp32 -> zero-padded bf16 ------------------------------
#define W2OFF 13312
#define W3OFF 59904
__global__ __launch_bounds__(256) void k_wcvt(const float* __restrict__ w1,
    const float* __restrict__ w2, const float* __restrict__ w3,
    unsigned short* __restrict__ wbf){
  int i = blockIdx.x * 256 + threadIdx.x;
  if (i < 208 * 64){
    int n = i >> 6, k = i & 63;
    float v = (n < 200 && k < 33) ? w1[n * 33 + k] : 0.f;
    wbf[i] = f2bf(v);
  } else if (i < W2OFF + 208 * 224){
    int j = i - W2OFF; int n = j / 224, k = j - n * 224;
    float v = (n < 200 && k < 200) ? w2[n * 200 + k] : 0.f;
    wbf[i] = f2bf(v);
  } else if (i < 84992){
    int j = i - W3OFF; int n = j / 224, k = j - n * 224;
    float v = (n < 100 && k < 200) ? w3[n * 200 + k] : 0.f;
    wbf[i] = f2bf(v);
  }
}

// ---------------- Fused MLP: 64-pixel tile, 3 layers, MFMA bf16 -------------------------
#define HSTR 232
__global__ __launch_bounds__(256, 1) void k_mlp(const float* __restrict__ zern,
    const float* __restrict__ b1f, const float* __restrict__ b2f,
    const float* __restrict__ b3f, const unsigned short* __restrict__ wbf,
    float* __restrict__ coefp){
  __shared__ char smem[59392];
  unsigned short* H1 = (unsigned short*)smem;
  float*          H3 = (float*)smem;
  unsigned short* XB = (unsigned short*)(smem + 29696);
  unsigned short* H2 = XB;
  int tid = threadIdx.x;
  int pix0 = blockIdx.x * 64;
  int lane = tid & 63, wv = tid >> 6;
  int ln = lane & 15, qd = lane >> 4;

  for (int e = tid; e < 2304; e += 256) ((int*)XB)[e] = 0;
  for (int e = tid; e < 768; e += 256){
    int m = e / 12, j = e - m * 12;
    ((int*)H1)[m * 116 + 104 + j] = 0;
  }
  __syncthreads();
  for (int e = tid; e < 64 * 33; e += 256){
    int m = e / 33, k = e - m * 33;
    XB[m * 72 + k] = f2bf(zern[(pix0 + m) * 35 + 2 + k]);
  }
  __syncthreads();

  // ---- layer 1 ----
  for (int nt = wv; nt < 13; nt += 4){
    int n = nt * 16 + ln;
    short8 b0 = *(const short8*)(wbf + n * 64 + qd * 8);
    short8 b1 = *(const short8*)(wbf + n * 64 + 32 + qd * 8);
    float bv = (n < 200) ? b1f[n] : 0.f;
    #pragma unroll
    for (int mt = 0; mt < 4; ++mt){
      float4v acc = {bv, bv, bv, bv};
      short8 a0 = *(const short8*)(XB + (mt * 16 + ln) * 72 + qd * 8);
      short8 a1 = *(const short8*)(XB + (mt * 16 + ln) * 72 + 32 + qd * 8);
      acc = __builtin_amdgcn_mfma_f32_16x16x32_bf16(a0, b0, acc, 0, 0, 0);
      acc = __builtin_amdgcn_mfma_f32_16x16x32_bf16(a1, b1, acc, 0, 0, 0);
      #pragma unroll
      for (int r = 0; r < 4; ++r)
        H1[(mt * 16 + qd * 4 + r) * HSTR + n] = f2bf(lrelu(acc[r]));
    }
  }
  __syncthreads();

  // ---- layer 2 ----
  for (int e = tid; e < 768; e += 256){
    int m = e / 12, j = e - m * 12;
    ((int*)H2)[m * 116 + 104 + j] = 0;
  }
  {
    const unsigned short* w2p = wbf + W2OFF;
    for (int nt = wv; nt < 13; nt += 4){
      int n = nt * 16 + ln;
      short8 bf[7];
      #pragma unroll
      for (int kc = 0; kc < 7; ++kc)
        bf[kc] = *(const short8*)(w2p + n * 224 + kc * 32 + qd * 8);
      float bv = (n < 200) ? b2f[n] : 0.f;
      #pragma unroll
      for (int mt = 0; mt < 4; ++mt){
        float4v acc = {bv, bv, bv, bv};
        #pragma unroll
        for (int kc = 0; kc < 7; ++kc){
          short8 af = *(const short8*)(H1 + (mt * 16 + ln) * HSTR + kc * 32 + qd * 8);
          acc = __builtin_amdgcn_mfma_f32_16x16x32_bf16(af, bf[kc], acc, 0, 0, 0);
        }
        #pragma unroll
        for (int r = 0; r < 4; ++r)
          H2[(mt * 16 + qd * 4 + r) * HSTR + n] = f2bf(lrelu(acc[r]));
      }
    }
  }
  __syncthreads();

  // ---- layer 3 ----
  {
    const unsigned short* w3p = wbf + W3OFF;
    for (int nt = wv; nt < 7; nt += 4){
      int n = nt * 16 + ln;
      short8 bf[7];
      #pragma unroll
      for (int kc = 0; kc < 7; ++kc)
        bf[kc] = *(const short8*)(w3p + n * 224 + kc * 32 + qd * 8);
      float bv = (n < 100) ? b3f[n] : 0.f;
      #pragma unroll
      for (int mt = 0; mt < 4; ++mt){
        float4v acc = {bv, bv, bv, bv};
        #pragma unroll
        for (int kc = 0; kc < 7; ++kc){
          short8 af = *(const short8*)(H2 + (mt * 16 + ln) * HSTR + kc * 32 + qd * 8);
          acc = __builtin_amdgcn_mfma_f32_16x16x32_bf16(af, bf[kc], acc, 0, 0, 0);
        }
        #pragma unroll
        for (int r = 0; r < 4; ++r)
          H3[(mt * 16 + qd * 4 + r) * 113 + n] = acc[r];
      }
    }
  }
  __syncthreads();

  for (int e = tid; e < 100 * 64; e += 256){
    int n = e >> 6, m = e & 63;
    coefp[n * HW + pix0 + m] = H3[m * 113 + n];
  }
}

// ---------------- K3 v3: vertical conv, half-height 16-col strips, b128 LDS reads -------
// bid < 1280: (c in 0..3, j in 0..9, h in 0..1, s in 0..15): S_{c,j} rows [h*128,h*128+128)
// bid >= 1280: (c in 0..2, h, s): Smu_{c,m} = vconv(tilt_c, mu_m), m=0..9
#define VSTR 196
__global__ __launch_bounds__(256) void k_vconv3(const float* __restrict__ tilt,
    const float* __restrict__ coefp, const float* __restrict__ bl,
    const float* __restrict__ mu, float* __restrict__ sbuf){
  __shared__ __align__(16) float sx[16 * VSTR];
  int tid = threadIdx.x;
  int bid = blockIdx.x;
  int tx = tid & 15, yg = tid >> 4;
  int yb = yg * 8;
  int t0 = tid >> 2, xq = tid & 3;

  if (bid < 1280){
    int cjh = bid >> 4;
    int c = cjh / 20;
    int rem = cjh - c * 20;
    int j = rem >> 1, h = rem & 1;
    int s = bid & 15;
    int x0 = s * 16;
    int ybase = h * 128 - 32;
    float4 treg[3];
    if (c < 3){
      const float* tc = tilt + c * HW;
      #pragma unroll
      for (int k = 0; k < 3; ++k){
        int gy = refl(ybase + t0 + k * 64);
        treg[k] = *(const float4*)(tc + gy * 256 + x0 + xq * 4);
      }
    }
    float acc[8];
    #pragma unroll
    for (int r = 0; r < 8; ++r) acc[r] = 0.f;
    for (int i = 0; i < 10; ++i){
      const float* cq = coefp + (i * 10 + j) * HW;
      __syncthreads();
      #pragma unroll
      for (int k = 0; k < 3; ++k){
        int t = t0 + k * 64;
        int gy = refl(ybase + t);
        float4 v = *(const float4*)(cq + gy * 256 + x0 + xq * 4);
        if (c < 3){ v.x *= treg[k].x; v.y *= treg[k].y; v.z *= treg[k].z; v.w *= treg[k].w; }
        int base = (xq * 4) * VSTR + t;
        sx[base] = v.x; sx[base + VSTR] = v.y; sx[base + 2 * VSTR] = v.z; sx[base + 3 * VSTR] = v.w;
      }
      __syncthreads();
      const float* col = sx + tx * VSTR + yb;
      for (int u = 0; u < 64; u += 4){
        float4 wa = *(const float4*)(col + u);
        float4 wb = *(const float4*)(col + u + 4);
        float4 wc = *(const float4*)(col + u + 8);
        float w[12] = {wa.x, wa.y, wa.z, wa.w, wb.x, wb.y, wb.z, wb.w, wc.x, wc.y, wc.z, wc.w};
        float k0 = bl[u * 10 + i],       k1 = bl[(u + 1) * 10 + i],
              k2 = bl[(u + 2) * 10 + i], k3 = bl[(u + 3) * 10 + i];
        #pragma unroll
        for (int r = 0; r < 8; ++r)
          acc[r] += k0 * w[r] + k1 * w[r + 1] + k2 * w[r + 2] + k3 * w[r + 3];
      }
      float k64 = bl[640 + i];
      float4 wa = *(const float4*)(col + 64);
      float4 wb = *(const float4*)(col + 68);
      float w8[8] = {wa.x, wa.y, wa.z, wa.w, wb.x, wb.y, wb.z, wb.w};
      #pragma unroll
      for (int r = 0; r < 8; ++r) acc[r] += k64 * w8[r];
    }
    float* S = sbuf + (c * 10 + j) * HW;
    #pragma unroll
    for (int r = 0; r < 8; ++r)
      S[(h * 128 + yb + r) * 256 + x0 + tx] = acc[r];
  } else {
    int b2 = bid - 1280;
    int ch = b2 >> 4;
    int c = ch >> 1, h = ch & 1;
    int s = b2 & 15;
    int x0 = s * 16;
    int ybase = h * 128 - 32;
    const float* tc = tilt + c * HW;
    #pragma unroll
    for (int k = 0; k < 3; ++k){
      int t = t0 + k * 64;
      int gy = refl(ybase + t);
      float4 v = *(const float4*)(tc + gy * 256 + x0 + xq * 4);
      int base = (xq * 4) * VSTR + t;
      sx[base] = v.x; sx[base + VSTR] = v.y; sx[base + 2 * VSTR] = v.z; sx[base + 3 * VSTR] = v.w;
    }
    __syncthreads();
    const float* col = sx + tx * VSTR + yb;
    for (int m = 0; m < 10; ++m){
      float acc[8];
      #pragma unroll
      for (int r = 0; r < 8; ++r) acc[r] = 0.f;
      for (int u = 0; u < 64; u += 4){
        float4 wa = *(const float4*)(col + u);
        float4 wb = *(const float4*)(col + u + 4);
        float4 wc = *(const float4*)(col + u + 8);
        float w[12] = {wa.x, wa.y, wa.z, wa.w, wb.x, wb.y, wb.z, wb.w, wc.x, wc.y, wc.z, wc.w};
        float k0 = mu[u * 10 + m],       k1 = mu[(u + 1) * 10 + m],
              k2 = mu[(u + 2) * 10 + m], k3 = mu[(u + 3) * 10 + m];
        #pragma unroll
        for (int r = 0; r < 8; ++r)
          acc[r] += k0 * w[r] + k1 * w[r + 1] + k2 * w[r + 2] + k3 * w[r + 3];
      }
      float k64 = mu[640 + m];
      float4 wa = *(const float4*)(col + 64);
      float4 wb = *(const float4*)(col + 68);
      float w8[8] = {wa.x, wa.y, wa.z, wa.w, wb.x, wb.y, wb.z, wb.w};
      #pragma unroll
      for (int r = 0; r < 8; ++r) acc[r] += k64 * w8[r];
      float* S = sbuf + (40 + c * 10 + m) * HW;
      #pragma unroll
      for (int r = 0; r < 8; ++r)
        S[(h * 128 + yb + r) * 256 + x0 + tx] = acc[r];
    }
  }
}

// ---------------- K4 v3: horizontal conv, 7 plane-groups x 64 y-tiles -------------------
// grp 0..2: num_br[tgt]  = sum_j hconv(S_{tgt,j}, R_j)      -> accb[tgt]
// grp 3:    den          = sum_j hconv(S_{3,j},  R_j)       -> accb[3]
// grp 4..6: num_mu[tgt]  = sum_m hconv(Smu_{tgt,m}, mu_m)   -> numB[tgt]
__global__ __launch_bounds__(256) void k_hconv3(const float* __restrict__ sbuf,
    const float* __restrict__ br, const float* __restrict__ mu,
    float* __restrict__ accb, float* __restrict__ numB){
  __shared__ __align__(16) float sr[4][320];
  int tid = threadIdx.x;
  int grp = blockIdx.x >> 6;
  int yt = blockIdx.x & 63;
  int r = tid >> 6, xg = tid & 63, x0 = xg * 4;
  const float* base; const float* kp; float* dst;
  if (grp < 3)      { base = sbuf + grp * 10 * HW;        kp = br; dst = accb + grp * HW; }
  else if (grp == 3){ base = sbuf + 30 * HW;              kp = br; dst = accb + 3 * HW; }
  else              { int t = grp - 4; base = sbuf + (40 + t * 10) * HW; kp = mu; dst = numB + t * HW; }
  float a0 = 0.f, a1 = 0.f, a2 = 0.f, a3 = 0.f;
  for (int p = 0; p < 10; ++p){
    const float* plane = base + p * HW;
    __syncthreads();
    for (int e = tid; e < 1280; e += 256){
      int rr = e / 320, ii = e - rr * 320;
      sr[rr][ii] = plane[(yt * 4 + rr) * 256 + refl(ii - 32)];
    }
    __syncthreads();
    float4 av = *(const float4*)&sr[r][x0];
    for (int u = 0; u < 64; u += 4){
      float4 bv = *(const float4*)&sr[r][x0 + u + 4];
      float k0 = kp[u * 10 + p],       k1 = kp[(u + 1) * 10 + p],
            k2 = kp[(u + 2) * 10 + p], k3 = kp[(u + 3) * 10 + p];
      a0 += k0 * av.x + k1 * av.y + k2 * av.z + k3 * av.w;
      a1 += k0 * av.y + k1 * av.z + k2 * av.w + k3 * bv.x;
      a2 += k0 * av.z + k1 * av.w + k2 * bv.x + k3 * bv.y;
      a3 += k0 * av.w + k1 * bv.x + k2 * bv.y + k3 * bv.z;
      av = bv;
    }
    float k64 = kp[640 + p];
    a0 += k64 * av.x; a1 += k64 * av.y; a2 += k64 * av.z; a3 += k64 * av.w;
  }
  float4 res = {a0, a1, a2, a3};
  *(float4*)(dst + (yt * 4 + r) * 256 + x0) = res;
}

// ---------------- K5: out = (numA + numB) / (den + muC) ---------------------------------
__global__ __launch_bounds__(256) void k_final(const float* __restrict__ accb,
                                               const float* __restrict__ numB,
                                               const float* __restrict__ mu,
                                               float* __restrict__ out){
  int pix = blockIdx.x * 256 + threadIdx.x;
  float muC = 0.f;
  #pragma unroll
  for (int m = 0; m < 10; ++m){
    float s = 0.f;
    for (int u = 0; u < 65; ++u) s += mu[u * 10 + m];
    muC += s * s;
  }
  float inv = 1.f / (accb[3 * HW + pix] + muC);
  #pragma unroll
  for (int cc = 0; cc < 3; ++cc)
    out[cc * HW + pix] = (accb[cc * HW + pix] + numB[cc * HW + pix]) * inv;
}

extern "C" void kernel_launch(void* const* d_in, const int* in_sizes, int n_in,
                              void* d_out, int out_size, void* d_ws, size_t ws_size,
                              hipStream_t stream) {
  const float* img  = (const float*)d_in[0];
  const float* zern = (const float*)d_in[1];
  const float* w1   = (const float*)d_in[2];
  const float* b1   = (const float*)d_in[3];
  const float* w2   = (const float*)d_in[4];
  const float* b2   = (const float*)d_in[5];
  const float* w3   = (const float*)d_in[6];
  const float* b3   = (const float*)d_in[7];
  const float* bl   = (const float*)d_in[8];
  const float* br   = (const float*)d_in[9];
  const float* mu   = (const float*)d_in[10];
  float* out = (float*)d_out;

  float* w     = (float*)d_ws;
  float* tilt  = w;              // planes [0,3)
  float* coefp = w + 3 * HW;     // planes [3,103); planes [3,6) reused as numB after vconv3
  float* numB  = w + 3 * HW;
  float* sbuf  = w + 103 * HW;   // planes [103,173): 40 S + 30 Smu
  float* accb  = w + 213 * HW;   // planes [213,217)
  unsigned short* wbf = (unsigned short*)sbuf; // bf16 weights, dead before vconv3 writes

  k_gridsample<<<256, 256, 0, stream>>>(img, zern, tilt);
  k_wcvt<<<332, 256, 0, stream>>>(w1, w2, w3, wbf);
  k_mlp<<<1024, 256, 0, stream>>>(zern, b1, b2, b3, wbf, coefp);
  k_vconv3<<<1376, 256, 0, stream>>>(tilt, coefp, bl, mu, sbuf);
  k_hconv3<<<448, 256, 0, stream>>>(sbuf, br, mu, accb, numB);
  k_final<<<256, 256, 0, stream>>>(accb, numB, mu, out);
}

// Round 6
// 241.950 us; speedup vs baseline: 5.9223x; 1.0392x over previous
//
#include <hip/hip_runtime.h>

#define HW 65536

typedef __attribute__((ext_vector_type(8))) short short8;
typedef __attribute__((ext_vector_type(4))) float float4v;

__device__ __forceinline__ int refl(int i){ if (i < 0) i = -i; if (i > 255) i = 510 - i; return i; }
__device__ __forceinline__ float lrelu(float x){ return x > 0.f ? x : 0.01f * x; }
__device__ __forceinline__ unsigned short f2bf(float x){
  union { float f; unsigned int u; } v; v.f = x;
  unsigned int r = v.u + 0x7fff + ((v.u >> 16) & 1);
  return (unsigned short)(r >> 16);
}

// ---------------- K1: bilinear grid sample (border, align_corners=False) ----------------
__global__ __launch_bounds__(256) void k_gridsample(const float* __restrict__ img,
                                                    const float* __restrict__ zern,
                                                    float* __restrict__ tilt){
  int x = threadIdx.x, y = blockIdx.x;
  int pix = y * 256 + x;
  float px = zern[pix * 35 + 0], py = zern[pix * 35 + 1];
  float ix = ((float)x + px) * (256.f / 255.f) - 0.5f;
  float iy = ((float)y + py) * (256.f / 255.f) - 0.5f;
  ix = fminf(fmaxf(ix, 0.f), 255.f);
  iy = fminf(fmaxf(iy, 0.f), 255.f);
  float x0f = floorf(ix), y0f = floorf(iy);
  float wx = ix - x0f, wy = iy - y0f;
  int x0 = (int)x0f, y0 = (int)y0f;
  int x1 = min(x0 + 1, 255), y1 = min(y0 + 1, 255);
  #pragma unroll
  for (int c = 0; c < 3; ++c){
    const float* im = img + c * HW;
    float g00 = im[y0 * 256 + x0], g01 = im[y0 * 256 + x1];
    float g10 = im[y1 * 256 + x0], g11 = im[y1 * 256 + x1];
    float top = g00 * (1.f - wx) + g01 * wx;
    float bot = g10 * (1.f - wx) + g11 * wx;
    tilt[c * HW + pix] = top * (1.f - wy) + bot * wy;
  }
}

// ---------------- Weight convert: fp32 -> zero-padded bf16 ------------------------------
#define W2OFF 13312
#define W3OFF 59904
__global__ __launch_bounds__(256) void k_wcvt(const float* __restrict__ w1,
    const float* __restrict__ w2, const float* __restrict__ w3,
    unsigned short* __restrict__ wbf){
  int i = blockIdx.x * 256 + threadIdx.x;
  if (i < 208 * 64){
    int n = i >> 6, k = i & 63;
    float v = (n < 200 && k < 33) ? w1[n * 33 + k] : 0.f;
    wbf[i] = f2bf(v);
  } else if (i < W2OFF + 208 * 224){
    int j = i - W2OFF; int n = j / 224, k = j - n * 224;
    float v = (n < 200 && k < 200) ? w2[n * 200 + k] : 0.f;
    wbf[i] = f2bf(v);
  } else if (i < 84992){
    int j = i - W3OFF; int n = j / 224, k = j - n * 224;
    float v = (n < 100 && k < 200) ? w3[n * 200 + k] : 0.f;
    wbf[i] = f2bf(v);
  }
}

// ---------------- Fused MLP: 64-pixel tile, 3 layers, MFMA bf16 -------------------------
#define HSTR 232
__global__ __launch_bounds__(256, 1) void k_mlp(const float* __restrict__ zern,
    const float* __restrict__ b1f, const float* __restrict__ b2f,
    const float* __restrict__ b3f, const unsigned short* __restrict__ wbf,
    float* __restrict__ coefp){
  __shared__ char smem[59392];
  unsigned short* H1 = (unsigned short*)smem;
  float*          H3 = (float*)smem;
  unsigned short* XB = (unsigned short*)(smem + 29696);
  unsigned short* H2 = XB;
  int tid = threadIdx.x;
  int pix0 = blockIdx.x * 64;
  int lane = tid & 63, wv = tid >> 6;
  int ln = lane & 15, qd = lane >> 4;

  for (int e = tid; e < 2304; e += 256) ((int*)XB)[e] = 0;
  for (int e = tid; e < 768; e += 256){
    int m = e / 12, j = e - m * 12;
    ((int*)H1)[m * 116 + 104 + j] = 0;
  }
  __syncthreads();
  for (int e = tid; e < 64 * 33; e += 256){
    int m = e / 33, k = e - m * 33;
    XB[m * 72 + k] = f2bf(zern[(pix0 + m) * 35 + 2 + k]);
  }
  __syncthreads();

  // ---- layer 1 ----
  for (int nt = wv; nt < 13; nt += 4){
    int n = nt * 16 + ln;
    short8 b0 = *(const short8*)(wbf + n * 64 + qd * 8);
    short8 b1 = *(const short8*)(wbf + n * 64 + 32 + qd * 8);
    float bv = (n < 200) ? b1f[n] : 0.f;
    #pragma unroll
    for (int mt = 0; mt < 4; ++mt){
      float4v acc = {bv, bv, bv, bv};
      short8 a0 = *(const short8*)(XB + (mt * 16 + ln) * 72 + qd * 8);
      short8 a1 = *(const short8*)(XB + (mt * 16 + ln) * 72 + 32 + qd * 8);
      acc = __builtin_amdgcn_mfma_f32_16x16x32_bf16(a0, b0, acc, 0, 0, 0);
      acc = __builtin_amdgcn_mfma_f32_16x16x32_bf16(a1, b1, acc, 0, 0, 0);
      #pragma unroll
      for (int r = 0; r < 4; ++r)
        H1[(mt * 16 + qd * 4 + r) * HSTR + n] = f2bf(lrelu(acc[r]));
    }
  }
  __syncthreads();

  // ---- layer 2 ----
  for (int e = tid; e < 768; e += 256){
    int m = e / 12, j = e - m * 12;
    ((int*)H2)[m * 116 + 104 + j] = 0;
  }
  {
    const unsigned short* w2p = wbf + W2OFF;
    for (int nt = wv; nt < 13; nt += 4){
      int n = nt * 16 + ln;
      short8 bf[7];
      #pragma unroll
      for (int kc = 0; kc < 7; ++kc)
        bf[kc] = *(const short8*)(w2p + n * 224 + kc * 32 + qd * 8);
      float bv = (n < 200) ? b2f[n] : 0.f;
      #pragma unroll
      for (int mt = 0; mt < 4; ++mt){
        float4v acc = {bv, bv, bv, bv};
        #pragma unroll
        for (int kc = 0; kc < 7; ++kc){
          short8 af = *(const short8*)(H1 + (mt * 16 + ln) * HSTR + kc * 32 + qd * 8);
          acc = __builtin_amdgcn_mfma_f32_16x16x32_bf16(af, bf[kc], acc, 0, 0, 0);
        }
        #pragma unroll
        for (int r = 0; r < 4; ++r)
          H2[(mt * 16 + qd * 4 + r) * HSTR + n] = f2bf(lrelu(acc[r]));
      }
    }
  }
  __syncthreads();

  // ---- layer 3 ----
  {
    const unsigned short* w3p = wbf + W3OFF;
    for (int nt = wv; nt < 7; nt += 4){
      int n = nt * 16 + ln;
      short8 bf[7];
      #pragma unroll
      for (int kc = 0; kc < 7; ++kc)
        bf[kc] = *(const short8*)(w3p + n * 224 + kc * 32 + qd * 8);
      float bv = (n < 100) ? b3f[n] : 0.f;
      #pragma unroll
      for (int mt = 0; mt < 4; ++mt){
        float4v acc = {bv, bv, bv, bv};
        #pragma unroll
        for (int kc = 0; kc < 7; ++kc){
          short8 af = *(const short8*)(H2 + (mt * 16 + ln) * HSTR + kc * 32 + qd * 8);
          acc = __builtin_amdgcn_mfma_f32_16x16x32_bf16(af, bf[kc], acc, 0, 0, 0);
        }
        #pragma unroll
        for (int r = 0; r < 4; ++r)
          H3[(mt * 16 + qd * 4 + r) * 113 + n] = acc[r];
      }
    }
  }
  __syncthreads();

  for (int e = tid; e < 100 * 64; e += 256){
    int n = e >> 6, m = e & 63;
    coefp[n * HW + pix0 + m] = H3[m * 113 + n];
  }
}

// ---------------- vertical conv pass: rolling 20-float register ring --------------------
// col points at LDS column (stride-1 in rows, 16B aligned). kv: taps at kv[u*10], kv[640].
// acc[r] += sum_u kv[u*10] * col[u + r], r = 0..15  (col holds rows yb..yb+79)
__device__ __forceinline__ void vpass(const float* __restrict__ col,
                                      const float* __restrict__ kv, float acc[16]){
  float w[20];
  #pragma unroll
  for (int k = 0; k < 5; ++k){
    float4 v = *(const float4*)(col + 4 * k);
    w[4 * k] = v.x; w[4 * k + 1] = v.y; w[4 * k + 2] = v.z; w[4 * k + 3] = v.w;
  }
  #pragma unroll
  for (int u = 0; u < 64; u += 4){
    float k0 = kv[u * 10], k1 = kv[(u + 1) * 10], k2 = kv[(u + 2) * 10], k3 = kv[(u + 3) * 10];
    #pragma unroll
    for (int r = 0; r < 16; ++r)
      acc[r] += k0 * w[(u + r) % 20] + k1 * w[(u + r + 1) % 20]
              + k2 * w[(u + r + 2) % 20] + k3 * w[(u + r + 3) % 20];
    if (u < 60){
      float4 v = *(const float4*)(col + u + 20);
      int b = u % 20;
      w[b] = v.x; w[b + 1] = v.y; w[b + 2] = v.z; w[b + 3] = v.w;
    }
  }
  float k64 = kv[640];
  #pragma unroll
  for (int r = 0; r < 16; ++r) acc[r] += k64 * w[(64 + r) % 20];
}

// ---------------- K3 v4: vertical conv, full-height 16-col strips, split-i --------------
// bid < 1280: (c 0..3, j 0..9, ih 0..1, s 0..15): partial S_{c,j} over i in [ih*5, ih*5+5)
//             -> (ih ? sbufB : sbufA)[(c*10+j)]
// bid >= 1280: (c 0..2, mh 0..1, s 0..15): Smu_{c,m} for m in [mh*5, mh*5+5) -> smu[c*10+m]
#define VSTR 324
__global__ __launch_bounds__(256) void k_vconv4(const float* __restrict__ tilt,
    const float* __restrict__ coefp, const float* __restrict__ bl,
    const float* __restrict__ mu, float* __restrict__ sbufA,
    float* __restrict__ sbufB, float* __restrict__ smu){
  __shared__ __align__(16) float sx[16 * VSTR];
  int tid = threadIdx.x;
  int bid = blockIdx.x;
  int tx = tid & 15, yg = tid >> 4;
  int yb = yg * 16;
  int t0 = tid >> 2, xq = tid & 3;

  if (bid < 1280){
    int s = bid & 15;
    int t = bid >> 4;           // 0..79
    int c = t / 20;
    int rem = t - c * 20;
    int j = rem >> 1, ih = rem & 1;
    int i0 = ih * 5;
    int x0 = s * 16;
    float4 treg[5];
    if (c < 3){
      const float* tc = tilt + c * HW;
      #pragma unroll
      for (int k = 0; k < 5; ++k){
        int gy = refl(t0 + k * 64 - 32);
        treg[k] = *(const float4*)(tc + gy * 256 + x0 + xq * 4);
      }
    }
    float acc[16];
    #pragma unroll
    for (int r = 0; r < 16; ++r) acc[r] = 0.f;
    for (int ii = 0; ii < 5; ++ii){
      int i = i0 + ii;
      const float* cq = coefp + (i * 10 + j) * HW;
      __syncthreads();
      #pragma unroll
      for (int k = 0; k < 5; ++k){
        int tt = t0 + k * 64;
        int gy = refl(tt - 32);
        float4 v = *(const float4*)(cq + gy * 256 + x0 + xq * 4);
        if (c < 3){ v.x *= treg[k].x; v.y *= treg[k].y; v.z *= treg[k].z; v.w *= treg[k].w; }
        int base = (xq * 4) * VSTR + tt;
        sx[base] = v.x; sx[base + VSTR] = v.y; sx[base + 2 * VSTR] = v.z; sx[base + 3 * VSTR] = v.w;
      }
      __syncthreads();
      vpass(sx + tx * VSTR + yb, bl + i, acc);
    }
    float* S = (ih ? sbufB : sbufA) + (c * 10 + j) * HW;
    #pragma unroll
    for (int r = 0; r < 16; ++r)
      S[(yb + r) * 256 + x0 + tx] = acc[r];
  } else {
    int b2 = bid - 1280;
    int s = b2 & 15;
    int t2 = b2 >> 4;           // 0..5
    int c = t2 >> 1, mh = t2 & 1;
    int x0 = s * 16;
    const float* tc = tilt + c * HW;
    #pragma unroll
    for (int k = 0; k < 5; ++k){
      int tt = t0 + k * 64;
      int gy = refl(tt - 32);
      float4 v = *(const float4*)(tc + gy * 256 + x0 + xq * 4);
      int base = (xq * 4) * VSTR + tt;
      sx[base] = v.x; sx[base + VSTR] = v.y; sx[base + 2 * VSTR] = v.z; sx[base + 3 * VSTR] = v.w;
    }
    __syncthreads();
    const float* col = sx + tx * VSTR + yb;
    for (int mm = 0; mm < 5; ++mm){
      int m = mh * 5 + mm;
      float acc[16];
      #pragma unroll
      for (int r = 0; r < 16; ++r) acc[r] = 0.f;
      vpass(col, mu + m, acc);
      float* S = smu + (c * 10 + m) * HW;
      #pragma unroll
      for (int r = 0; r < 16; ++r)
        S[(yb + r) * 256 + x0 + tx] = acc[r];
    }
  }
}

// ---------------- K4 v4: horizontal conv, 14 groups x 64 y-tiles ------------------------
// grp 0..7:  (tgt 0..3, half h): sum_{j in [5h,5h+5)} hconv(A_{tgt,j}+B_{tgt,j}, R_j) -> part[grp]
// grp 8..13: (tgt 0..2, half h): sum_{m in [5h,5h+5)} hconv(Smu_{tgt,m}, mu_m)       -> part[grp]
__global__ __launch_bounds__(256) void k_hconv4(const float* __restrict__ sbufA,
    const float* __restrict__ sbufB, const float* __restrict__ smu,
    const float* __restrict__ br, const float* __restrict__ mu,
    float* __restrict__ part){
  __shared__ __align__(16) float sr[4][320];
  int tid = threadIdx.x;
  int grp = blockIdx.x >> 6;
  int yt = blockIdx.x & 63;
  int r = tid >> 6, xg = tid & 63, x0 = xg * 4;
  int isbr = (grp < 8);
  int tgt, h;
  if (isbr){ tgt = grp >> 1; h = grp & 1; }
  else     { int g2 = grp - 8; tgt = g2 >> 1; h = g2 & 1; }
  const float* kp = isbr ? br : mu;
  float a0 = 0.f, a1 = 0.f, a2 = 0.f, a3 = 0.f;
  for (int p = 0; p < 5; ++p){
    int col = h * 5 + p;
    __syncthreads();
    if (isbr){
      const float* pa = sbufA + (tgt * 10 + col) * HW;
      const float* pb = sbufB + (tgt * 10 + col) * HW;
      for (int e = tid; e < 1280; e += 256){
        int rr = e / 320, ii = e - rr * 320;
        int g = (yt * 4 + rr) * 256 + refl(ii - 32);
        sr[rr][ii] = pa[g] + pb[g];
      }
    } else {
      const float* pm = smu + (tgt * 10 + col) * HW;
      for (int e = tid; e < 1280; e += 256){
        int rr = e / 320, ii = e - rr * 320;
        sr[rr][ii] = pm[(yt * 4 + rr) * 256 + refl(ii - 32)];
      }
    }
    __syncthreads();
    float4 av = *(const float4*)&sr[r][x0];
    for (int u = 0; u < 64; u += 4){
      float4 bv = *(const float4*)&sr[r][x0 + u + 4];
      float k0 = kp[u * 10 + col],       k1 = kp[(u + 1) * 10 + col],
            k2 = kp[(u + 2) * 10 + col], k3 = kp[(u + 3) * 10 + col];
      a0 += k0 * av.x + k1 * av.y + k2 * av.z + k3 * av.w;
      a1 += k0 * av.y + k1 * av.z + k2 * av.w + k3 * bv.x;
      a2 += k0 * av.z + k1 * av.w + k2 * bv.x + k3 * bv.y;
      a3 += k0 * av.w + k1 * bv.x + k2 * bv.y + k3 * bv.z;
      av = bv;
    }
    float k64 = kp[640 + col];
    a0 += k64 * av.x; a1 += k64 * av.y; a2 += k64 * av.z; a3 += k64 * av.w;
  }
  float4 res = {a0, a1, a2, a3};
  *(float4*)(part + grp * HW + (yt * 4 + r) * 256 + x0) = res;
}

// ---------------- K5: out_c = (P2c+P2c+1+P8+2c+P9+2c) / (P6+P7+muC) ---------------------
__global__ __launch_bounds__(256) void k_final(const float* __restrict__ part,
                                               const float* __restrict__ mu,
                                               float* __restrict__ out){
  int pix = blockIdx.x * 256 + threadIdx.x;
  float muC = 0.f;
  #pragma unroll
  for (int m = 0; m < 10; ++m){
    float s = 0.f;
    for (int u = 0; u < 65; ++u) s += mu[u * 10 + m];
    muC += s * s;
  }
  float den = part[6 * HW + pix] + part[7 * HW + pix] + muC;
  float inv = 1.f / den;
  #pragma unroll
  for (int c = 0; c < 3; ++c){
    float num = part[(2 * c) * HW + pix] + part[(2 * c + 1) * HW + pix]
              + part[(8 + 2 * c) * HW + pix] + part[(9 + 2 * c) * HW + pix];
    out[c * HW + pix] = num * inv;
  }
}

extern "C" void kernel_launch(void* const* d_in, const int* in_sizes, int n_in,
                              void* d_out, int out_size, void* d_ws, size_t ws_size,
                              hipStream_t stream) {
  const float* img  = (const float*)d_in[0];
  const float* zern = (const float*)d_in[1];
  const float* w1   = (const float*)d_in[2];
  const float* b1   = (const float*)d_in[3];
  const float* w2   = (const float*)d_in[4];
  const float* b2   = (const float*)d_in[5];
  const float* w3   = (const float*)d_in[6];
  const float* b3   = (const float*)d_in[7];
  const float* bl   = (const float*)d_in[8];
  const float* br   = (const float*)d_in[9];
  const float* mu   = (const float*)d_in[10];
  float* out = (float*)d_out;

  float* w     = (float*)d_ws;
  float* tilt  = w;              // planes [0,3)
  float* coefp = w + 3 * HW;     // planes [3,103); dead after vconv4
  float* part  = w + 3 * HW;     // planes [3,17): hconv partials (reuse coefp region)
  float* sbufA = w + 103 * HW;   // planes [103,143)
  float* sbufB = w + 143 * HW;   // planes [143,183)
  float* smu   = w + 183 * HW;   // planes [183,213)
  unsigned short* wbf = (unsigned short*)sbufA; // bf16 weights, dead before vconv4 writes

  k_gridsample<<<256, 256, 0, stream>>>(img, zern, tilt);
  k_wcvt<<<332, 256, 0, stream>>>(w1, w2, w3, wbf);
  k_mlp<<<1024, 256, 0, stream>>>(zern, b1, b2, b3, wbf, coefp);
  k_vconv4<<<1376, 256, 0, stream>>>(tilt, coefp, bl, mu, sbufA, sbufB, smu);
  k_hconv4<<<896, 256, 0, stream>>>(sbufA, sbufB, smu, br, mu, part);
  k_final<<<256, 256, 0, stream>>>(part, mu, out);
}